// Round 8
// baseline (479.693 us; speedup 1.0000x reference)
//
#include <hip/hip_runtime.h>
#include <cstdint>
#include <cstddef>

constexpr int N_NODES  = 20000;
constexpr int N_PAD    = 20096;   // 157 * 128
constexpr int N_EDGES  = 160000;
constexpr int N_GRAPHS = 16;
constexpr int SEQ_L    = 2048;
constexpr int F_IN     = 1024;
constexpr int D_OUT    = 128;
constexpr int N_DESC   = 80;
constexpr int K_PAD    = 104;     // conv: 80 padded to 96 for MFMA, 104 stride for banks
constexpr int N_CCH    = 16;      // conv: L-chunks of 128
constexpr int ELL_CAP  = 64;      // max degree capacity (Poisson(8): P(>64) ~ 1e-10)
constexpr int AGG_NB   = 16;      // agg: nodes per block
constexpr int ROWB     = N_PAD / 128;      // 157
constexpr int NWG_GEMM = 2 * ROWB * 8;     // 2512, divisible by 8
constexpr float SLOPE  = 0.01f;

// P1 fused-kernel block ranges
constexpr int P1_CONV_END  = 1024;                    // 16 ch * 16 g * 4 br
constexpr int P1_FILL_END  = P1_CONV_END + 2 * 625;   // 160000/256 = 625 per branch
constexpr int P1_CONVT_END = P1_FILL_END + 2 * 1024;  // 32*32 per branch
constexpr int P1_CAST_END  = P1_CONVT_END + 2 * 20096;
constexpr int P1_SMEM      = 53248;                   // 2 * 128*104*2 bytes

typedef short bf16x8 __attribute__((ext_vector_type(8)));
typedef float f32x4  __attribute__((ext_vector_type(4)));

__device__ __forceinline__ float leaky(float x) { return x > 0.f ? x : SLOPE * x; }
__device__ __forceinline__ ushort f2bf(float f) {
  uint32_t u = __float_as_uint(f);
  uint32_t r = (u + 0x7FFFu + ((u >> 16) & 1u)) >> 16;
  return (ushort)r;
}
__device__ __forceinline__ float bf2f(ushort u) { return __uint_as_float(((uint32_t)u) << 16); }

__device__ __forceinline__ int lower_bound_i(const int* __restrict__ arr, int n, int val) {
  int lo = 0, hi = n;
  while (lo < hi) { int mid = (lo + hi) >> 1; if (arr[mid] < val) lo = mid + 1; else hi = mid; }
  return lo;
}

// ================= P1: conv_mfma | fill_ell | convT | cast_pad (one launch) =================
__global__ __launch_bounds__(256) void p1_fused(
    const float* __restrict__ m0, const float* __restrict__ m1,
    const float* __restrict__ m2, const float* __restrict__ m3,
    const float* __restrict__ Wc0, const float* __restrict__ Wc1,
    const float* __restrict__ Wc2, const float* __restrict__ Wc3,
    float* __restrict__ pmax,
    const int* __restrict__ e0, const int* __restrict__ e1,
    int* __restrict__ cnt, int* __restrict__ ell,
    const float* __restrict__ Wg0, const float* __restrict__ Wg1,
    ushort* __restrict__ wtbf,
    const float* __restrict__ x0, const float* __restrict__ x1,
    ushort* __restrict__ xbf) {
  extern __shared__ char smem[];
  const int bid = blockIdx.x;
  const int t = threadIdx.x;

  if (bid < P1_CONV_END) {
    // ---- conv1d(k=1) via MFMA: [128 L-rows x 80] @ [80 x 128], max over rows ----
    ushort* lA = (ushort*)smem;                 // [128][K_PAD]
    ushort* lB = (ushort*)(smem + 26624);       // [128 col][K_PAD]
    float*  smax = (float*)smem;                // aliases lA after compute
    const int ch = bid & 15, g = (bid >> 4) & 15, br = bid >> 8;
    const float* m = br == 0 ? m0 : br == 1 ? m1 : br == 2 ? m2 : m3;
    const float* W = br == 0 ? Wc0 : br == 1 ? Wc1 : br == 2 ? Wc2 : Wc3;
    const int lane = t & 63, w = t >> 6;

    for (int i = t; i < N_DESC * D_OUT; i += 256) {
      int k = i >> 7, col = i & 127;
      lB[col * K_PAD + k] = f2bf(W[i]);
    }
    for (int i = t; i < 128 * 16; i += 256) {
      int col = i >> 4, k = 80 + (i & 15);
      lB[col * K_PAD + k] = 0;
    }
    const float4* mg4 = (const float4*)(m + ((size_t)g * SEQ_L + (size_t)ch * 128) * N_DESC);
#pragma unroll
    for (int j = 0; j < 10; ++j) {
      int fi = t + j * 256;
      int row = fi / 20, off = fi - row * 20;
      float4 v = mg4[fi];
      ushort4 o;
      o.x = f2bf(v.x); o.y = f2bf(v.y); o.z = f2bf(v.z); o.w = f2bf(v.w);
      *(ushort4*)(lA + row * K_PAD + off * 4) = o;
    }
    if (t < 128) {
      ushort4 z4 = {0, 0, 0, 0};
      *(ushort4*)(lA + t * K_PAD + 80) = z4;
      *(ushort4*)(lA + t * K_PAD + 84) = z4;
      *(ushort4*)(lA + t * K_PAD + 88) = z4;
      *(ushort4*)(lA + t * K_PAD + 92) = z4;
    }
    __syncthreads();

    const int frow = lane & 15, fk = (lane >> 4) * 8;
    f32x4 acc[2][8] = {};
#pragma unroll
    for (int ks = 0; ks < 3; ++ks) {
      bf16x8 af[2], bfr[8];
#pragma unroll
      for (int mm = 0; mm < 2; ++mm)
        af[mm] = *(const bf16x8*)(lA + (w * 32 + mm * 16 + frow) * K_PAD + ks * 32 + fk);
#pragma unroll
      for (int n = 0; n < 8; ++n)
        bfr[n] = *(const bf16x8*)(lB + (n * 16 + frow) * K_PAD + ks * 32 + fk);
#pragma unroll
      for (int mm = 0; mm < 2; ++mm)
#pragma unroll
        for (int n = 0; n < 8; ++n)
          acc[mm][n] = __builtin_amdgcn_mfma_f32_16x16x32_bf16(af[mm], bfr[n], acc[mm][n], 0, 0, 0);
    }
    __syncthreads();

#pragma unroll
    for (int n = 0; n < 8; ++n) {
      float v = acc[0][n][0];
#pragma unroll
      for (int j = 1; j < 4; ++j) v = fmaxf(v, acc[0][n][j]);
#pragma unroll
      for (int j = 0; j < 4; ++j) v = fmaxf(v, acc[1][n][j]);
      v = fmaxf(v, __shfl_xor(v, 16, 64));
      v = fmaxf(v, __shfl_xor(v, 32, 64));
      if (lane < 16) smax[w * D_OUT + n * 16 + lane] = v;
    }
    __syncthreads();
    if (t < D_OUT) {
      float v = fmaxf(fmaxf(smax[t], smax[D_OUT + t]),
                      fmaxf(smax[2 * D_OUT + t], smax[3 * D_OUT + t]));
      pmax[(((size_t)br * N_GRAPHS + g) * N_CCH + ch) * D_OUT + t] = v;
    }
  } else if (bid < P1_FILL_END) {
    // ---- build ELL adjacency ----
    int fb = bid - P1_CONV_END;
    int z = fb >= 625;
    int i = (fb - z * 625) * 256 + t;
    const int* src = z ? e1 : e0;
    const int* dst = src + N_EDGES;
    int d = dst[i];
    int pos = atomicAdd(&cnt[z * N_NODES + d], 1);
    if (pos < ELL_CAP) ell[((size_t)z * N_NODES + d) * ELL_CAP + pos] = src[i];
  } else if (bid < P1_CONVT_END) {
    // ---- W [K=1024][N=1024] f32 -> Wt [N][K] bf16 ----
    float (*tile)[33] = (float(*)[33])smem;
    int cb = bid - P1_FILL_END;
    int z = cb >= 1024;
    int cb2 = cb - z * 1024;
    const float* W = z ? Wg1 : Wg0;
    const int k0 = (cb2 & 31) * 32, n0 = (cb2 >> 5) * 32;
    const int tc = t & 31, tr = t >> 5;
#pragma unroll
    for (int q = 0; q < 4; ++q) {
      int r = tr + q * 8;
      tile[r][tc] = W[(size_t)(k0 + r) * F_IN + n0 + tc];
    }
    __syncthreads();
    ushort* Wz = wtbf + (size_t)z * F_IN * F_IN;
#pragma unroll
    for (int q = 0; q < 4; ++q) {
      int r = tr + q * 8;
      Wz[(size_t)(n0 + r) * F_IN + k0 + tc] = f2bf(tile[tc][r]);
    }
  } else {
    // ---- x cast/pad ----
    int cb = bid - P1_CONVT_END;
    int z = cb >= 20096;
    int cb2 = cb - z * 20096;
    const float* in = z ? x1 : x0;
    size_t i = ((size_t)cb2 * 256 + t) * 4;
    int row = (int)(i >> 10);
    ushort4 o;
    if (row < N_NODES) {
      float4 v = *(const float4*)(in + i);
      o.x = f2bf(v.x); o.y = f2bf(v.y); o.z = f2bf(v.z); o.w = f2bf(v.w);
    } else {
      o.x = o.y = o.z = o.w = 0;
    }
    *(ushort4*)(xbf + (size_t)z * N_PAD * F_IN + i) = o;
  }
}

// ========== bf16 MFMA GEMM, BK=32 (m97 structure), dinv-scaled epilogue ==========
// stores hs[row] = rsqrt(cnt[row]+1) * (x @ W)[row]  (bf16)
__global__ __launch_bounds__(256) void gemm2(const ushort* __restrict__ A,
                                             const ushort* __restrict__ Bt,
                                             const int* __restrict__ cnt,
                                             ushort* __restrict__ C) {
  const int bid = blockIdx.x;
  const int swz = (bid & 7) * (NWG_GEMM / 8) + (bid >> 3);
  const int br  = swz / (ROWB * 8);
  const int rem = swz - br * (ROWB * 8);
  const int rowb = rem >> 3, colb = rem & 7;

  const ushort* Az = A + (size_t)br * N_PAD * F_IN;
  const ushort* Bz = Bt + (size_t)br * F_IN * F_IN;
  ushort* Cz = C + (size_t)br * N_PAD * F_IN;
  const int* cz = cnt + br * N_NODES;

  __shared__ ushort lA[128 * 32];
  __shared__ ushort lB[128 * 32];
  const int t = threadIdx.x;
  const int lane = t & 63;
  const int w = t >> 6;
  const int wr = w >> 1, wc = w & 1;
  const int brow = rowb * 128;
  const int bcol = colb * 128;

  const int si = w * 2;
  const int srow0 = si * 16 + (lane >> 2);
  const int srow1 = (si + 1) * 16 + (lane >> 2);
  const int skk = (lane & 3) * 8;
  const ushort* gA0 = Az + (size_t)(brow + srow0) * F_IN + skk;
  const ushort* gA1 = Az + (size_t)(brow + srow1) * F_IN + skk;
  const ushort* gB0 = Bz + (size_t)(bcol + srow0) * F_IN + skk;
  const ushort* gB1 = Bz + (size_t)(bcol + srow1) * F_IN + skk;
  ushort* lA0 = lA + si * 512;
  ushort* lA1 = lA + (si + 1) * 512;
  ushort* lB0 = lB + si * 512;
  ushort* lB1 = lB + (si + 1) * 512;

  f32x4 acc[4][4] = {};
  const int frow = lane & 15;
  const int fk = (lane >> 4) * 8;

  for (int k0 = 0; k0 < F_IN; k0 += 32) {
    __builtin_amdgcn_global_load_lds((const __attribute__((address_space(1))) void*)(gA0 + k0),
                                     (__attribute__((address_space(3))) void*)lA0, 16, 0, 0);
    __builtin_amdgcn_global_load_lds((const __attribute__((address_space(1))) void*)(gA1 + k0),
                                     (__attribute__((address_space(3))) void*)lA1, 16, 0, 0);
    __builtin_amdgcn_global_load_lds((const __attribute__((address_space(1))) void*)(gB0 + k0),
                                     (__attribute__((address_space(3))) void*)lB0, 16, 0, 0);
    __builtin_amdgcn_global_load_lds((const __attribute__((address_space(1))) void*)(gB1 + k0),
                                     (__attribute__((address_space(3))) void*)lB1, 16, 0, 0);
    __syncthreads();
    bf16x8 af[4], bfr[4];
#pragma unroll
    for (int m = 0; m < 4; ++m)
      af[m] = *(const bf16x8*)(lA + (wr * 64 + m * 16 + frow) * 32 + fk);
#pragma unroll
    for (int n = 0; n < 4; ++n)
      bfr[n] = *(const bf16x8*)(lB + (wc * 64 + n * 16 + frow) * 32 + fk);
#pragma unroll
    for (int m = 0; m < 4; ++m)
#pragma unroll
      for (int n = 0; n < 4; ++n)
        acc[m][n] = __builtin_amdgcn_mfma_f32_16x16x32_bf16(af[m], bfr[n], acc[m][n], 0, 0, 0);
    __syncthreads();
  }

#pragma unroll
  for (int m = 0; m < 4; ++m) {
    const int row0 = brow + wr * 64 + m * 16 + (lane >> 4) * 4;
#pragma unroll
    for (int j = 0; j < 4; ++j) {
      const int row = row0 + j;
      const float dv = (row < N_NODES) ? rsqrtf((float)(cz[row] + 1)) : 0.f;
#pragma unroll
      for (int n = 0; n < 4; ++n) {
        const int col = bcol + wc * 64 + n * 16 + (lane & 15);
        Cz[(size_t)row * F_IN + col] = f2bf(acc[m][n][j] * dv);
      }
    }
  }
}

// ===== GCN aggregate + mean-pool fused: pool[g] += leaky(din*(hs[n] + sum_nb hs[s]) + b) =====
// 16 consecutive nodes per block (sorted batch -> <=2 graph runs); partials in registers,
// one atomicAdd set per (thread, graph-run).
__global__ __launch_bounds__(256) void gcn_agg_pool(const ushort* __restrict__ hs,
                                                    const int* __restrict__ cnt,
                                                    const int* __restrict__ ell,
                                                    const int* __restrict__ bt0,
                                                    const int* __restrict__ bt1,
                                                    const float* __restrict__ b0,
                                                    const float* __restrict__ b1,
                                                    float* __restrict__ pool) {
  const int z = blockIdx.y;
  const int sub = threadIdx.x >> 7;     // waves 0-1: sub=0, waves 2-3: sub=1
  const int lt = threadIdx.x & 127;     // 8 bf16 elems each
  const int node0 = blockIdx.x * AGG_NB;
  const ushort* hz = hs + (size_t)z * N_PAD * F_IN;
  const int* cz = cnt + z * N_NODES;
  const int* batch = z ? bt1 : bt0;
  const float* bias = z ? b1 : b0;
  float* poolz = pool + (size_t)z * N_GRAPHS * F_IN;

  float bv[8];
  *(float4*)(bv)     = ((const float4*)bias)[lt * 2];
  *(float4*)(bv + 4) = ((const float4*)bias)[lt * 2 + 1];

  float pp[8] = {};
  int curg = batch[node0 + sub];
  for (int np = 0; np < AGG_NB / 2; ++np) {
    const int node = node0 + np * 2 + sub;
    const int g = batch[node];
    if (g != curg) {
#pragma unroll
      for (int j = 0; j < 8; ++j) atomicAdd(&poolz[curg * F_IN + lt * 8 + j], pp[j]);
#pragma unroll
      for (int j = 0; j < 8; ++j) pp[j] = 0.f;
      curg = g;
    }
    const int deg = cz[node];
    const float din = rsqrtf((float)(deg + 1));
    bf16x8 hv = ((const bf16x8*)(hz + (size_t)node * F_IN))[lt];
    float acc[8];
#pragma unroll
    for (int j = 0; j < 8; ++j) acc[j] = bf2f((ushort)hv[j]);
    const int* el = ell + ((size_t)z * N_NODES + node) * ELL_CAP;
    const int ne = min(deg, ELL_CAP);
    int e = 0;
    for (; e + 2 <= ne; e += 2) {
      int s0 = el[e], s1 = el[e + 1];
      bf16x8 v0 = ((const bf16x8*)(hz + (size_t)s0 * F_IN))[lt];
      bf16x8 v1 = ((const bf16x8*)(hz + (size_t)s1 * F_IN))[lt];
#pragma unroll
      for (int j = 0; j < 8; ++j) acc[j] += bf2f((ushort)v0[j]) + bf2f((ushort)v1[j]);
    }
    if (e < ne) {
      int s0 = el[e];
      bf16x8 v0 = ((const bf16x8*)(hz + (size_t)s0 * F_IN))[lt];
#pragma unroll
      for (int j = 0; j < 8; ++j) acc[j] += bf2f((ushort)v0[j]);
    }
#pragma unroll
    for (int j = 0; j < 8; ++j) pp[j] += leaky(din * acc[j] + bv[j]);
  }
#pragma unroll
  for (int j = 0; j < 8; ++j) atomicAdd(&poolz[curg * F_IN + lt * 8 + j], pp[j]);
}

// ================= T1: conv_reduce | fc, fused =================
__global__ __launch_bounds__(256) void tail1(const float* __restrict__ pmax,
                                             const float* __restrict__ cb0, const float* __restrict__ cb1,
                                             const float* __restrict__ cb2, const float* __restrict__ cb3,
                                             const float* __restrict__ pool,
                                             const int* __restrict__ bt0, const int* __restrict__ bt1,
                                             const float* __restrict__ W0, const float* __restrict__ W1,
                                             const float* __restrict__ fb0, const float* __restrict__ fb1,
                                             float* __restrict__ combined) {
  __shared__ float p[2][F_IN];
  const int bid = blockIdx.x;
  const int t = threadIdx.x;
  if (bid < 32) {
    int i = bid * 256 + t;
    int br = i >> 11;
    int g = (i >> 7) & 15;
    int d = i & 127;
    const float* pm = pmax + ((size_t)(br * N_GRAPHS + g) * N_CCH) * D_OUT + d;
    float best = -3.4e38f;
#pragma unroll
    for (int ch = 0; ch < N_CCH; ++ch) best = fmaxf(best, pm[ch * D_OUT]);
    const float* bias = br == 0 ? cb0 : br == 1 ? cb1 : br == 2 ? cb2 : cb3;
    combined[g * (6 * D_OUT) + 2 * D_OUT + br * D_OUT + d] = leaky(best + bias[d]);
  } else {
    int idx = (bid - 32) * 2 + (t >> 7);
    int z = idx >> 4, g = idx & 15;
    int tt = t & 127, sub = t >> 7;
    const int* batch = z ? bt1 : bt0;
    const float* W = z ? W1 : W0;
    const float* bias = z ? fb1 : fb0;
    int lo = lower_bound_i(batch, N_NODES, g);
    int hi = lower_bound_i(batch, N_NODES, g + 1);
    float inv = 1.0f / (float)max(hi - lo, 1);
    const float* pg = pool + ((size_t)z * N_GRAPHS + g) * F_IN;
    for (int k = tt; k < F_IN; k += 128) p[sub][k] = pg[k] * inv;
    __syncthreads();
    float acc = 0.f;
    for (int k = 0; k < F_IN; ++k) acc = fmaf(p[sub][k], W[k * D_OUT + tt], acc);
    combined[g * (6 * D_OUT) + z * D_OUT + tt] = leaky(acc + bias[tt]);
  }
}

// ================= final linear =================
__global__ __launch_bounds__(256) void final_kernel(const float* __restrict__ combined,
                                                    const float* __restrict__ Wf,
                                                    const float* __restrict__ bf,
                                                    float* __restrict__ out) {
  const int g = blockIdx.x;
  const int t = threadIdx.x;
  float acc = 0.f;
  for (int k = t; k < 6 * D_OUT; k += 256) acc = fmaf(combined[g * 6 * D_OUT + k], Wf[k], acc);
  __shared__ float red[256];
  red[t] = acc;
  __syncthreads();
  for (int s = 128; s > 0; s >>= 1) {
    if (t < s) red[t] += red[t + s];
    __syncthreads();
  }
  if (t == 0) out[g] = red[0] + bf[0];
}

extern "C" void kernel_launch(void* const* d_in, const int* in_sizes, int n_in,
                              void* d_out, int out_size, void* d_ws, size_t ws_size,
                              hipStream_t stream) {
  const float* p1x  = (const float*)d_in[0];
  const int*   e1   = (const int*)d_in[1];
  const int*   bt1  = (const int*)d_in[2];
  const float* p2x  = (const float*)d_in[3];
  const int*   e2   = (const int*)d_in[4];
  const int*   bt2  = (const int*)d_in[5];
  const float* m1s  = (const float*)d_in[6];
  const float* m1f  = (const float*)d_in[7];
  const float* m2s  = (const float*)d_in[8];
  const float* m2f  = (const float*)d_in[9];
  const float* Wg1  = (const float*)d_in[10];
  const float* bg1  = (const float*)d_in[11];
  const float* Wfc1 = (const float*)d_in[12];
  const float* bfc1 = (const float*)d_in[13];
  const float* Wg2  = (const float*)d_in[14];
  const float* bg2  = (const float*)d_in[15];
  const float* Wfc2 = (const float*)d_in[16];
  const float* bfc2 = (const float*)d_in[17];
  const float* Wm1s = (const float*)d_in[18];
  const float* bm1s = (const float*)d_in[19];
  const float* Wm1f = (const float*)d_in[20];
  const float* bm1f = (const float*)d_in[21];
  const float* Wm2s = (const float*)d_in[22];
  const float* bm2s = (const float*)d_in[23];
  const float* Wm2f = (const float*)d_in[24];
  const float* bm2f = (const float*)d_in[25];
  const float* Wfin = (const float*)d_in[26];
  const float* bfin = (const float*)d_in[27];
  float* out = (float*)d_out;

  char* base = (char*)d_ws;
  size_t off = 0;
  auto alloc = [&](size_t bytes) -> void* {
    void* p = base + off;
    off = (off + bytes + 255) & ~(size_t)255;
    return p;
  };
  ushort* xbf    = (ushort*)alloc((size_t)2 * N_PAD * F_IN * 2);
  ushort* wtbf   = (ushort*)alloc((size_t)2 * F_IN * F_IN * 2);
  ushort* h      = (ushort*)alloc((size_t)2 * N_PAD * F_IN * 2);
  // contiguous zero-init region: cnt, pool
  size_t zoff0 = off;
  int*    cnt    = (int*)alloc((size_t)2 * N_NODES * 4);
  float*  pool   = (float*)alloc((size_t)2 * N_GRAPHS * F_IN * 4);
  size_t zbytes = off - zoff0;
  int*    ell    = (int*)alloc((size_t)2 * N_NODES * ELL_CAP * 4);
  float*  combined = (float*)alloc((size_t)N_GRAPHS * 6 * D_OUT * 4);
  float*  pmax   = (float*)alloc((size_t)4 * N_GRAPHS * N_CCH * D_OUT * 4);
  (void)ws_size; (void)in_sizes; (void)n_in; (void)out_size;

  hipMemsetAsync((char*)base + zoff0, 0, zbytes, stream);

  // P1: conv_mfma | fill_ell | convT | cast  (one fused launch)
  p1_fused<<<P1_CAST_END, 256, P1_SMEM, stream>>>(
      m1s, m1f, m2s, m2f, Wm1s, Wm1f, Wm2s, Wm2f, pmax,
      e1, e2, cnt, ell,
      Wg1, Wg2, wtbf,
      p1x, p2x, xbf);

  gemm2<<<NWG_GEMM, 256, 0, stream>>>(xbf, wtbf, cnt, h);

  gcn_agg_pool<<<dim3(N_NODES / AGG_NB, 2), 256, 0, stream>>>(h, cnt, ell, bt1, bt2, bg1, bg2, pool);

  tail1<<<48, 256, 0, stream>>>(pmax, bm1s, bm1f, bm2s, bm2f,
                                pool, bt1, bt2, Wfc1, Wfc2, bfc1, bfc2, combined);

  final_kernel<<<N_GRAPHS, 256, 0, stream>>>(combined, Wfin, bfin, out);
}

// Round 9
// 375.490 us; speedup vs baseline: 1.2775x; 1.2775x over previous
//
#include <hip/hip_runtime.h>
#include <cstdint>
#include <cstddef>

constexpr int N_NODES  = 20000;
constexpr int N_PAD    = 20096;   // 157 * 128
constexpr int N_EDGES  = 160000;
constexpr int N_GRAPHS = 16;
constexpr int SEQ_L    = 2048;
constexpr int F_IN     = 1024;
constexpr int D_OUT    = 128;
constexpr int N_DESC   = 80;
constexpr int K_PAD    = 104;     // conv: 80 padded to 96 for MFMA, 104 stride for banks
constexpr int N_CCH    = 16;      // conv: L-chunks of 128
constexpr int ELL_CAP  = 64;      // max degree capacity (Poisson(8): P(>64) ~ 1e-10)
constexpr int S_SLICES = 32;      // agg: slices per graph
constexpr int ROWB     = N_PAD / 128;      // 157
constexpr int NWG_GEMM = 2 * ROWB * 8;     // 2512, divisible by 8
constexpr float SLOPE  = 0.01f;

// P1 fused-kernel block ranges
constexpr int P1_CONV_END  = 1024;                    // 16 ch * 16 g * 4 br
constexpr int P1_FILL_END  = P1_CONV_END + 2 * 625;   // 160000/256 = 625 per branch
constexpr int P1_CONVT_END = P1_FILL_END + 2 * 1024;  // 32*32 per branch
constexpr int P1_CAST_END  = P1_CONVT_END + 2 * 20096;
constexpr int P1_SMEM      = 53248;                   // 2 * 128*104*2 bytes

typedef short bf16x8 __attribute__((ext_vector_type(8)));
typedef float f32x4  __attribute__((ext_vector_type(4)));

__device__ __forceinline__ float leaky(float x) { return x > 0.f ? x : SLOPE * x; }
__device__ __forceinline__ ushort f2bf(float f) {
  uint32_t u = __float_as_uint(f);
  uint32_t r = (u + 0x7FFFu + ((u >> 16) & 1u)) >> 16;
  return (ushort)r;
}
__device__ __forceinline__ float bf2f(ushort u) { return __uint_as_float(((uint32_t)u) << 16); }

__device__ __forceinline__ int lower_bound_i(const int* __restrict__ arr, int n, int val) {
  int lo = 0, hi = n;
  while (lo < hi) { int mid = (lo + hi) >> 1; if (arr[mid] < val) lo = mid + 1; else hi = mid; }
  return lo;
}

// ================= P1: conv_mfma | fill_ell | convT | cast_pad (one launch) =================
__global__ __launch_bounds__(256) void p1_fused(
    const float* __restrict__ m0, const float* __restrict__ m1,
    const float* __restrict__ m2, const float* __restrict__ m3,
    const float* __restrict__ Wc0, const float* __restrict__ Wc1,
    const float* __restrict__ Wc2, const float* __restrict__ Wc3,
    float* __restrict__ pmax,
    const int* __restrict__ e0, const int* __restrict__ e1,
    int* __restrict__ cnt, int* __restrict__ ell,
    const float* __restrict__ Wg0, const float* __restrict__ Wg1,
    ushort* __restrict__ wtbf,
    const float* __restrict__ x0, const float* __restrict__ x1,
    ushort* __restrict__ xbf) {
  extern __shared__ char smem[];
  const int bid = blockIdx.x;
  const int t = threadIdx.x;

  if (bid < P1_CONV_END) {
    // ---- conv1d(k=1) via MFMA: [128 L-rows x 80] @ [80 x 128], max over rows ----
    ushort* lA = (ushort*)smem;                 // [128][K_PAD]
    ushort* lB = (ushort*)(smem + 26624);       // [128 col][K_PAD]
    float*  smax = (float*)smem;                // aliases lA after compute
    const int ch = bid & 15, g = (bid >> 4) & 15, br = bid >> 8;
    const float* m = br == 0 ? m0 : br == 1 ? m1 : br == 2 ? m2 : m3;
    const float* W = br == 0 ? Wc0 : br == 1 ? Wc1 : br == 2 ? Wc2 : Wc3;
    const int lane = t & 63, w = t >> 6;

    for (int i = t; i < N_DESC * D_OUT; i += 256) {
      int k = i >> 7, col = i & 127;
      lB[col * K_PAD + k] = f2bf(W[i]);
    }
    for (int i = t; i < 128 * 16; i += 256) {
      int col = i >> 4, k = 80 + (i & 15);
      lB[col * K_PAD + k] = 0;
    }
    const float4* mg4 = (const float4*)(m + ((size_t)g * SEQ_L + (size_t)ch * 128) * N_DESC);
#pragma unroll
    for (int j = 0; j < 10; ++j) {
      int fi = t + j * 256;
      int row = fi / 20, off = fi - row * 20;
      float4 v = mg4[fi];
      ushort4 o;
      o.x = f2bf(v.x); o.y = f2bf(v.y); o.z = f2bf(v.z); o.w = f2bf(v.w);
      *(ushort4*)(lA + row * K_PAD + off * 4) = o;
    }
    if (t < 128) {
      ushort4 z4 = {0, 0, 0, 0};
      *(ushort4*)(lA + t * K_PAD + 80) = z4;
      *(ushort4*)(lA + t * K_PAD + 84) = z4;
      *(ushort4*)(lA + t * K_PAD + 88) = z4;
      *(ushort4*)(lA + t * K_PAD + 92) = z4;
    }
    __syncthreads();

    const int frow = lane & 15, fk = (lane >> 4) * 8;
    f32x4 acc[2][8] = {};
#pragma unroll
    for (int ks = 0; ks < 3; ++ks) {
      bf16x8 af[2], bfr[8];
#pragma unroll
      for (int mm = 0; mm < 2; ++mm)
        af[mm] = *(const bf16x8*)(lA + (w * 32 + mm * 16 + frow) * K_PAD + ks * 32 + fk);
#pragma unroll
      for (int n = 0; n < 8; ++n)
        bfr[n] = *(const bf16x8*)(lB + (n * 16 + frow) * K_PAD + ks * 32 + fk);
#pragma unroll
      for (int mm = 0; mm < 2; ++mm)
#pragma unroll
        for (int n = 0; n < 8; ++n)
          acc[mm][n] = __builtin_amdgcn_mfma_f32_16x16x32_bf16(af[mm], bfr[n], acc[mm][n], 0, 0, 0);
    }
    __syncthreads();

#pragma unroll
    for (int n = 0; n < 8; ++n) {
      float v = acc[0][n][0];
#pragma unroll
      for (int j = 1; j < 4; ++j) v = fmaxf(v, acc[0][n][j]);
#pragma unroll
      for (int j = 0; j < 4; ++j) v = fmaxf(v, acc[1][n][j]);
      v = fmaxf(v, __shfl_xor(v, 16, 64));
      v = fmaxf(v, __shfl_xor(v, 32, 64));
      if (lane < 16) smax[w * D_OUT + n * 16 + lane] = v;
    }
    __syncthreads();
    if (t < D_OUT) {
      float v = fmaxf(fmaxf(smax[t], smax[D_OUT + t]),
                      fmaxf(smax[2 * D_OUT + t], smax[3 * D_OUT + t]));
      pmax[(((size_t)br * N_GRAPHS + g) * N_CCH + ch) * D_OUT + t] = v;
    }
  } else if (bid < P1_FILL_END) {
    // ---- build ELL adjacency ----
    int fb = bid - P1_CONV_END;
    int z = fb >= 625;
    int i = (fb - z * 625) * 256 + t;
    const int* src = z ? e1 : e0;
    const int* dst = src + N_EDGES;
    int d = dst[i];
    int pos = atomicAdd(&cnt[z * N_NODES + d], 1);
    if (pos < ELL_CAP) ell[((size_t)z * N_NODES + d) * ELL_CAP + pos] = src[i];
  } else if (bid < P1_CONVT_END) {
    // ---- W [K=1024][N=1024] f32 -> Wt [N][K] bf16 ----
    float (*tile)[33] = (float(*)[33])smem;
    int cb = bid - P1_FILL_END;
    int z = cb >= 1024;
    int cb2 = cb - z * 1024;
    const float* W = z ? Wg1 : Wg0;
    const int k0 = (cb2 & 31) * 32, n0 = (cb2 >> 5) * 32;
    const int tc = t & 31, tr = t >> 5;
#pragma unroll
    for (int q = 0; q < 4; ++q) {
      int r = tr + q * 8;
      tile[r][tc] = W[(size_t)(k0 + r) * F_IN + n0 + tc];
    }
    __syncthreads();
    ushort* Wz = wtbf + (size_t)z * F_IN * F_IN;
#pragma unroll
    for (int q = 0; q < 4; ++q) {
      int r = tr + q * 8;
      Wz[(size_t)(n0 + r) * F_IN + k0 + tc] = f2bf(tile[tc][r]);
    }
  } else {
    // ---- x cast/pad ----
    int cb = bid - P1_CONVT_END;
    int z = cb >= 20096;
    int cb2 = cb - z * 20096;
    const float* in = z ? x1 : x0;
    size_t i = ((size_t)cb2 * 256 + t) * 4;
    int row = (int)(i >> 10);
    ushort4 o;
    if (row < N_NODES) {
      float4 v = *(const float4*)(in + i);
      o.x = f2bf(v.x); o.y = f2bf(v.y); o.z = f2bf(v.z); o.w = f2bf(v.w);
    } else {
      o.x = o.y = o.z = o.w = 0;
    }
    *(ushort4*)(xbf + (size_t)z * N_PAD * F_IN + i) = o;
  }
}

// ========== bf16 MFMA GEMM, BK=32 (m97 structure), dinv-scaled epilogue ==========
// stores hs[row] = rsqrt(cnt[row]+1) * (x @ W)[row]  (bf16)
__global__ __launch_bounds__(256) void gemm2(const ushort* __restrict__ A,
                                             const ushort* __restrict__ Bt,
                                             const int* __restrict__ cnt,
                                             ushort* __restrict__ C) {
  const int bid = blockIdx.x;
  const int swz = (bid & 7) * (NWG_GEMM / 8) + (bid >> 3);
  const int br  = swz / (ROWB * 8);
  const int rem = swz - br * (ROWB * 8);
  const int rowb = rem >> 3, colb = rem & 7;

  const ushort* Az = A + (size_t)br * N_PAD * F_IN;
  const ushort* Bz = Bt + (size_t)br * F_IN * F_IN;
  ushort* Cz = C + (size_t)br * N_PAD * F_IN;
  const int* cz = cnt + br * N_NODES;

  __shared__ ushort lA[128 * 32];
  __shared__ ushort lB[128 * 32];
  const int t = threadIdx.x;
  const int lane = t & 63;
  const int w = t >> 6;
  const int wr = w >> 1, wc = w & 1;
  const int brow = rowb * 128;
  const int bcol = colb * 128;

  const int si = w * 2;
  const int srow0 = si * 16 + (lane >> 2);
  const int srow1 = (si + 1) * 16 + (lane >> 2);
  const int skk = (lane & 3) * 8;
  const ushort* gA0 = Az + (size_t)(brow + srow0) * F_IN + skk;
  const ushort* gA1 = Az + (size_t)(brow + srow1) * F_IN + skk;
  const ushort* gB0 = Bz + (size_t)(bcol + srow0) * F_IN + skk;
  const ushort* gB1 = Bz + (size_t)(bcol + srow1) * F_IN + skk;
  ushort* lA0 = lA + si * 512;
  ushort* lA1 = lA + (si + 1) * 512;
  ushort* lB0 = lB + si * 512;
  ushort* lB1 = lB + (si + 1) * 512;

  f32x4 acc[4][4] = {};
  const int frow = lane & 15;
  const int fk = (lane >> 4) * 8;

  for (int k0 = 0; k0 < F_IN; k0 += 32) {
    __builtin_amdgcn_global_load_lds((const __attribute__((address_space(1))) void*)(gA0 + k0),
                                     (__attribute__((address_space(3))) void*)lA0, 16, 0, 0);
    __builtin_amdgcn_global_load_lds((const __attribute__((address_space(1))) void*)(gA1 + k0),
                                     (__attribute__((address_space(3))) void*)lA1, 16, 0, 0);
    __builtin_amdgcn_global_load_lds((const __attribute__((address_space(1))) void*)(gB0 + k0),
                                     (__attribute__((address_space(3))) void*)lB0, 16, 0, 0);
    __builtin_amdgcn_global_load_lds((const __attribute__((address_space(1))) void*)(gB1 + k0),
                                     (__attribute__((address_space(3))) void*)lB1, 16, 0, 0);
    __syncthreads();
    bf16x8 af[4], bfr[4];
#pragma unroll
    for (int m = 0; m < 4; ++m)
      af[m] = *(const bf16x8*)(lA + (wr * 64 + m * 16 + frow) * 32 + fk);
#pragma unroll
    for (int n = 0; n < 4; ++n)
      bfr[n] = *(const bf16x8*)(lB + (wc * 64 + n * 16 + frow) * 32 + fk);
#pragma unroll
    for (int m = 0; m < 4; ++m)
#pragma unroll
      for (int n = 0; n < 4; ++n)
        acc[m][n] = __builtin_amdgcn_mfma_f32_16x16x32_bf16(af[m], bfr[n], acc[m][n], 0, 0, 0);
    __syncthreads();
  }

#pragma unroll
  for (int m = 0; m < 4; ++m) {
    const int row0 = brow + wr * 64 + m * 16 + (lane >> 4) * 4;
#pragma unroll
    for (int j = 0; j < 4; ++j) {
      const int row = row0 + j;
      const float dv = (row < N_NODES) ? rsqrtf((float)(cz[row] + 1)) : 0.f;
#pragma unroll
      for (int n = 0; n < 4; ++n) {
        const int col = bcol + wc * 64 + n * 16 + (lane & 15);
        Cz[(size_t)row * F_IN + col] = f2bf(acc[m][n][j] * dv);
      }
    }
  }
}

// ===== GCN aggregate + mean-pool fused, low-atomic version =====
// block = (graph g, slice, branch z); thread serially processes ~20 same-graph nodes,
// accumulates in registers; cross-sub combine in LDS; ONE atomic flush per block
// (4 atomics/thread). 1024 blocks -> ~1M atomic-floats (vs 5.1M in the regressed version).
__global__ __launch_bounds__(256) void gcn_agg_pool(const ushort* __restrict__ hs,
                                                    const int* __restrict__ cnt,
                                                    const int* __restrict__ ell,
                                                    const int* __restrict__ bt0,
                                                    const int* __restrict__ bt1,
                                                    const float* __restrict__ b0,
                                                    const float* __restrict__ b1,
                                                    float* __restrict__ pool) {
  __shared__ float lp[F_IN];
  const int g = blockIdx.x;
  const int slice = blockIdx.y;
  const int z = blockIdx.z;
  const int sub = threadIdx.x >> 7;     // 2-node parallel
  const int lt = threadIdx.x & 127;     // 8 features each
  const int* batch = z ? bt1 : bt0;
  const ushort* hz = hs + (size_t)z * N_PAD * F_IN;
  const int* cz = cnt + z * N_NODES;
  const float* bias = z ? b1 : b0;

  int lo = lower_bound_i(batch, N_NODES, g);
  int hi = lower_bound_i(batch, N_NODES, g + 1);
  int per = (hi - lo + S_SLICES - 1) / S_SLICES;
  int a = lo + slice * per;
  int b = min(a + per, hi);
  if (a >= b) return;   // uniform per block

  float bv[8];
  *(float4*)(bv)     = ((const float4*)bias)[lt * 2];
  *(float4*)(bv + 4) = ((const float4*)bias)[lt * 2 + 1];

  float pp[8] = {};
  for (int node = a + sub; node < b; node += 2) {
    const int deg = cz[node];
    const float din = rsqrtf((float)(deg + 1));
    bf16x8 hv = ((const bf16x8*)(hz + (size_t)node * F_IN))[lt];
    float acc[8];
#pragma unroll
    for (int j = 0; j < 8; ++j) acc[j] = bf2f((ushort)hv[j]);
    const int* el = ell + ((size_t)z * N_NODES + node) * ELL_CAP;
    const int ne = min(deg, ELL_CAP);
    int e = 0;
    for (; e + 2 <= ne; e += 2) {
      int s0 = el[e], s1 = el[e + 1];
      bf16x8 v0 = ((const bf16x8*)(hz + (size_t)s0 * F_IN))[lt];
      bf16x8 v1 = ((const bf16x8*)(hz + (size_t)s1 * F_IN))[lt];
#pragma unroll
      for (int j = 0; j < 8; ++j) acc[j] += bf2f((ushort)v0[j]) + bf2f((ushort)v1[j]);
    }
    if (e < ne) {
      int s0 = el[e];
      bf16x8 v0 = ((const bf16x8*)(hz + (size_t)s0 * F_IN))[lt];
#pragma unroll
      for (int j = 0; j < 8; ++j) acc[j] += bf2f((ushort)v0[j]);
    }
#pragma unroll
    for (int j = 0; j < 8; ++j) pp[j] += leaky(din * acc[j] + bv[j]);
  }

  // combine the two subs in LDS, then one flush per block
  if (sub == 0) {
    *(float4*)(&lp[lt * 8])     = *(const float4*)(pp);
    *(float4*)(&lp[lt * 8 + 4]) = *(const float4*)(pp + 4);
  }
  __syncthreads();
  if (sub == 1) {
#pragma unroll
    for (int j = 0; j < 8; ++j) lp[lt * 8 + j] += pp[j];
  }
  __syncthreads();
  float* pg = pool + ((size_t)z * N_GRAPHS + g) * F_IN;
#pragma unroll
  for (int q = 0; q < 4; ++q) {
    int i = threadIdx.x + q * 256;
    atomicAdd(&pg[i], lp[i]);
  }
}

// ================= T1: conv_reduce | fc, fused =================
__global__ __launch_bounds__(256) void tail1(const float* __restrict__ pmax,
                                             const float* __restrict__ cb0, const float* __restrict__ cb1,
                                             const float* __restrict__ cb2, const float* __restrict__ cb3,
                                             const float* __restrict__ pool,
                                             const int* __restrict__ bt0, const int* __restrict__ bt1,
                                             const float* __restrict__ W0, const float* __restrict__ W1,
                                             const float* __restrict__ fb0, const float* __restrict__ fb1,
                                             float* __restrict__ combined) {
  __shared__ float p[2][F_IN];
  const int bid = blockIdx.x;
  const int t = threadIdx.x;
  if (bid < 32) {
    int i = bid * 256 + t;
    int br = i >> 11;
    int g = (i >> 7) & 15;
    int d = i & 127;
    const float* pm = pmax + ((size_t)(br * N_GRAPHS + g) * N_CCH) * D_OUT + d;
    float best = -3.4e38f;
#pragma unroll
    for (int ch = 0; ch < N_CCH; ++ch) best = fmaxf(best, pm[ch * D_OUT]);
    const float* bias = br == 0 ? cb0 : br == 1 ? cb1 : br == 2 ? cb2 : cb3;
    combined[g * (6 * D_OUT) + 2 * D_OUT + br * D_OUT + d] = leaky(best + bias[d]);
  } else {
    int idx = (bid - 32) * 2 + (t >> 7);
    int z = idx >> 4, g = idx & 15;
    int tt = t & 127, sub = t >> 7;
    const int* batch = z ? bt1 : bt0;
    const float* W = z ? W1 : W0;
    const float* bias = z ? fb1 : fb0;
    int lo = lower_bound_i(batch, N_NODES, g);
    int hi = lower_bound_i(batch, N_NODES, g + 1);
    float inv = 1.0f / (float)max(hi - lo, 1);
    const float* pg = pool + ((size_t)z * N_GRAPHS + g) * F_IN;
    for (int k = tt; k < F_IN; k += 128) p[sub][k] = pg[k] * inv;
    __syncthreads();
    float acc = 0.f;
    for (int k = 0; k < F_IN; ++k) acc = fmaf(p[sub][k], W[k * D_OUT + tt], acc);
    combined[g * (6 * D_OUT) + z * D_OUT + tt] = leaky(acc + bias[tt]);
  }
}

// ================= final linear =================
__global__ __launch_bounds__(256) void final_kernel(const float* __restrict__ combined,
                                                    const float* __restrict__ Wf,
                                                    const float* __restrict__ bf,
                                                    float* __restrict__ out) {
  const int g = blockIdx.x;
  const int t = threadIdx.x;
  float acc = 0.f;
  for (int k = t; k < 6 * D_OUT; k += 256) acc = fmaf(combined[g * 6 * D_OUT + k], Wf[k], acc);
  __shared__ float red[256];
  red[t] = acc;
  __syncthreads();
  for (int s = 128; s > 0; s >>= 1) {
    if (t < s) red[t] += red[t + s];
    __syncthreads();
  }
  if (t == 0) out[g] = red[0] + bf[0];
}

extern "C" void kernel_launch(void* const* d_in, const int* in_sizes, int n_in,
                              void* d_out, int out_size, void* d_ws, size_t ws_size,
                              hipStream_t stream) {
  const float* p1x  = (const float*)d_in[0];
  const int*   e1   = (const int*)d_in[1];
  const int*   bt1  = (const int*)d_in[2];
  const float* p2x  = (const float*)d_in[3];
  const int*   e2   = (const int*)d_in[4];
  const int*   bt2  = (const int*)d_in[5];
  const float* m1s  = (const float*)d_in[6];
  const float* m1f  = (const float*)d_in[7];
  const float* m2s  = (const float*)d_in[8];
  const float* m2f  = (const float*)d_in[9];
  const float* Wg1  = (const float*)d_in[10];
  const float* bg1  = (const float*)d_in[11];
  const float* Wfc1 = (const float*)d_in[12];
  const float* bfc1 = (const float*)d_in[13];
  const float* Wg2  = (const float*)d_in[14];
  const float* bg2  = (const float*)d_in[15];
  const float* Wfc2 = (const float*)d_in[16];
  const float* bfc2 = (const float*)d_in[17];
  const float* Wm1s = (const float*)d_in[18];
  const float* bm1s = (const float*)d_in[19];
  const float* Wm1f = (const float*)d_in[20];
  const float* bm1f = (const float*)d_in[21];
  const float* Wm2s = (const float*)d_in[22];
  const float* bm2s = (const float*)d_in[23];
  const float* Wm2f = (const float*)d_in[24];
  const float* bm2f = (const float*)d_in[25];
  const float* Wfin = (const float*)d_in[26];
  const float* bfin = (const float*)d_in[27];
  float* out = (float*)d_out;

  char* base = (char*)d_ws;
  size_t off = 0;
  auto alloc = [&](size_t bytes) -> void* {
    void* p = base + off;
    off = (off + bytes + 255) & ~(size_t)255;
    return p;
  };
  ushort* xbf    = (ushort*)alloc((size_t)2 * N_PAD * F_IN * 2);
  ushort* wtbf   = (ushort*)alloc((size_t)2 * F_IN * F_IN * 2);
  ushort* h      = (ushort*)alloc((size_t)2 * N_PAD * F_IN * 2);
  // contiguous zero-init region: cnt, pool
  size_t zoff0 = off;
  int*    cnt    = (int*)alloc((size_t)2 * N_NODES * 4);
  float*  pool   = (float*)alloc((size_t)2 * N_GRAPHS * F_IN * 4);
  size_t zbytes = off - zoff0;
  int*    ell    = (int*)alloc((size_t)2 * N_NODES * ELL_CAP * 4);
  float*  combined = (float*)alloc((size_t)N_GRAPHS * 6 * D_OUT * 4);
  float*  pmax   = (float*)alloc((size_t)4 * N_GRAPHS * N_CCH * D_OUT * 4);
  (void)ws_size; (void)in_sizes; (void)n_in; (void)out_size;

  hipMemsetAsync((char*)base + zoff0, 0, zbytes, stream);

  // P1: conv_mfma | fill_ell | convT | cast  (one fused launch)
  p1_fused<<<P1_CAST_END, 256, P1_SMEM, stream>>>(
      m1s, m1f, m2s, m2f, Wm1s, Wm1f, Wm2s, Wm2f, pmax,
      e1, e2, cnt, ell,
      Wg1, Wg2, wtbf,
      p1x, p2x, xbf);

  gemm2<<<NWG_GEMM, 256, 0, stream>>>(xbf, wtbf, cnt, h);

  gcn_agg_pool<<<dim3(N_GRAPHS, S_SLICES, 2), 256, 0, stream>>>(h, cnt, ell, bt1, bt2, bg1, bg2, pool);

  tail1<<<48, 256, 0, stream>>>(pmax, bm1s, bm1f, bm2s, bm2f,
                                pool, bt1, bt2, Wfc1, Wfc2, bfc1, bfc2, combined);

  final_kernel<<<N_GRAPHS, 256, 0, stream>>>(combined, Wfin, bfin, out);
}

// Round 10
// 357.452 us; speedup vs baseline: 1.3420x; 1.0505x over previous
//
#include <hip/hip_runtime.h>
#include <cstdint>
#include <cstddef>

constexpr int N_NODES  = 20000;
constexpr int N_PAD    = 20096;   // 157 * 128
constexpr int N_EDGES  = 160000;
constexpr int N_GRAPHS = 16;
constexpr int SEQ_L    = 2048;
constexpr int F_IN     = 1024;
constexpr int D_OUT    = 128;
constexpr int N_DESC   = 80;
constexpr int K_PAD    = 104;     // conv: 80 padded to 96 for MFMA, 104 stride for banks
constexpr int N_CCH    = 16;      // conv: L-chunks of 128
constexpr int ELL_CAP  = 64;      // max degree capacity (Poisson(8): P(>64) ~ 1e-10)
constexpr int S_SLICES = 32;      // agg: slices per graph
constexpr int ROWB     = N_PAD / 128;      // 157
constexpr int NWG_GEMM = 2 * ROWB * 8;     // 2512, divisible by 8
constexpr float SLOPE  = 0.01f;

// P1 fused-kernel block ranges
constexpr int P1_CONV_END  = 1024;                    // 16 ch * 16 g * 4 br
constexpr int P1_FILL_END  = P1_CONV_END + 2 * 625;   // 160000/256 = 625 per branch
constexpr int P1_CONVT_END = P1_FILL_END + 2 * 1024;  // 32*32 per branch
constexpr int P1_CAST_END  = P1_CONVT_END + 2 * 20096;
constexpr int P1_SMEM      = 53248;                   // 2 * 128*104*2 bytes

typedef short bf16x8 __attribute__((ext_vector_type(8)));
typedef float f32x4  __attribute__((ext_vector_type(4)));

__device__ __forceinline__ float leaky(float x) { return x > 0.f ? x : SLOPE * x; }
__device__ __forceinline__ ushort f2bf(float f) {
  uint32_t u = __float_as_uint(f);
  uint32_t r = (u + 0x7FFFu + ((u >> 16) & 1u)) >> 16;
  return (ushort)r;
}
__device__ __forceinline__ float bf2f(ushort u) { return __uint_as_float(((uint32_t)u) << 16); }

__device__ __forceinline__ int lower_bound_i(const int* __restrict__ arr, int n, int val) {
  int lo = 0, hi = n;
  while (lo < hi) { int mid = (lo + hi) >> 1; if (arr[mid] < val) lo = mid + 1; else hi = mid; }
  return lo;
}

// ================= P1: conv_mfma | fill_ell | convT | cast_pad (one launch) =================
__global__ __launch_bounds__(256) void p1_fused(
    const float* __restrict__ m0, const float* __restrict__ m1,
    const float* __restrict__ m2, const float* __restrict__ m3,
    const float* __restrict__ Wc0, const float* __restrict__ Wc1,
    const float* __restrict__ Wc2, const float* __restrict__ Wc3,
    float* __restrict__ pmax,
    const int* __restrict__ e0, const int* __restrict__ e1,
    int* __restrict__ cnt, int* __restrict__ ell,
    const float* __restrict__ Wg0, const float* __restrict__ Wg1,
    ushort* __restrict__ wtbf,
    const float* __restrict__ x0, const float* __restrict__ x1,
    ushort* __restrict__ xbf) {
  extern __shared__ char smem[];
  const int bid = blockIdx.x;
  const int t = threadIdx.x;

  if (bid < P1_CONV_END) {
    // ---- conv1d(k=1) via MFMA: [128 L-rows x 80] @ [80 x 128], max over rows ----
    ushort* lA = (ushort*)smem;                 // [128][K_PAD]
    ushort* lB = (ushort*)(smem + 26624);       // [128 col][K_PAD]
    float*  smax = (float*)smem;                // aliases lA after compute
    const int ch = bid & 15, g = (bid >> 4) & 15, br = bid >> 8;
    const float* m = br == 0 ? m0 : br == 1 ? m1 : br == 2 ? m2 : m3;
    const float* W = br == 0 ? Wc0 : br == 1 ? Wc1 : br == 2 ? Wc2 : Wc3;
    const int lane = t & 63, w = t >> 6;

    for (int i = t; i < N_DESC * D_OUT; i += 256) {
      int k = i >> 7, col = i & 127;
      lB[col * K_PAD + k] = f2bf(W[i]);
    }
    for (int i = t; i < 128 * 16; i += 256) {
      int col = i >> 4, k = 80 + (i & 15);
      lB[col * K_PAD + k] = 0;
    }
    const float4* mg4 = (const float4*)(m + ((size_t)g * SEQ_L + (size_t)ch * 128) * N_DESC);
#pragma unroll
    for (int j = 0; j < 10; ++j) {
      int fi = t + j * 256;
      int row = fi / 20, off = fi - row * 20;
      float4 v = mg4[fi];
      ushort4 o;
      o.x = f2bf(v.x); o.y = f2bf(v.y); o.z = f2bf(v.z); o.w = f2bf(v.w);
      *(ushort4*)(lA + row * K_PAD + off * 4) = o;
    }
    if (t < 128) {
      ushort4 z4 = {0, 0, 0, 0};
      *(ushort4*)(lA + t * K_PAD + 80) = z4;
      *(ushort4*)(lA + t * K_PAD + 84) = z4;
      *(ushort4*)(lA + t * K_PAD + 88) = z4;
      *(ushort4*)(lA + t * K_PAD + 92) = z4;
    }
    __syncthreads();

    const int frow = lane & 15, fk = (lane >> 4) * 8;
    f32x4 acc[2][8] = {};
#pragma unroll
    for (int ks = 0; ks < 3; ++ks) {
      bf16x8 af[2], bfr[8];
#pragma unroll
      for (int mm = 0; mm < 2; ++mm)
        af[mm] = *(const bf16x8*)(lA + (w * 32 + mm * 16 + frow) * K_PAD + ks * 32 + fk);
#pragma unroll
      for (int n = 0; n < 8; ++n)
        bfr[n] = *(const bf16x8*)(lB + (n * 16 + frow) * K_PAD + ks * 32 + fk);
#pragma unroll
      for (int mm = 0; mm < 2; ++mm)
#pragma unroll
        for (int n = 0; n < 8; ++n)
          acc[mm][n] = __builtin_amdgcn_mfma_f32_16x16x32_bf16(af[mm], bfr[n], acc[mm][n], 0, 0, 0);
    }
    __syncthreads();

#pragma unroll
    for (int n = 0; n < 8; ++n) {
      float v = acc[0][n][0];
#pragma unroll
      for (int j = 1; j < 4; ++j) v = fmaxf(v, acc[0][n][j]);
#pragma unroll
      for (int j = 0; j < 4; ++j) v = fmaxf(v, acc[1][n][j]);
      v = fmaxf(v, __shfl_xor(v, 16, 64));
      v = fmaxf(v, __shfl_xor(v, 32, 64));
      if (lane < 16) smax[w * D_OUT + n * 16 + lane] = v;
    }
    __syncthreads();
    if (t < D_OUT) {
      float v = fmaxf(fmaxf(smax[t], smax[D_OUT + t]),
                      fmaxf(smax[2 * D_OUT + t], smax[3 * D_OUT + t]));
      pmax[(((size_t)br * N_GRAPHS + g) * N_CCH + ch) * D_OUT + t] = v;
    }
  } else if (bid < P1_FILL_END) {
    // ---- build ELL adjacency ----
    int fb = bid - P1_CONV_END;
    int z = fb >= 625;
    int i = (fb - z * 625) * 256 + t;
    const int* src = z ? e1 : e0;
    const int* dst = src + N_EDGES;
    int d = dst[i];
    int pos = atomicAdd(&cnt[z * N_NODES + d], 1);
    if (pos < ELL_CAP) ell[((size_t)z * N_NODES + d) * ELL_CAP + pos] = src[i];
  } else if (bid < P1_CONVT_END) {
    // ---- W [K=1024][N=1024] f32 -> Wt [N][K] bf16 ----
    float (*tile)[33] = (float(*)[33])smem;
    int cb = bid - P1_FILL_END;
    int z = cb >= 1024;
    int cb2 = cb - z * 1024;
    const float* W = z ? Wg1 : Wg0;
    const int k0 = (cb2 & 31) * 32, n0 = (cb2 >> 5) * 32;
    const int tc = t & 31, tr = t >> 5;
#pragma unroll
    for (int q = 0; q < 4; ++q) {
      int r = tr + q * 8;
      tile[r][tc] = W[(size_t)(k0 + r) * F_IN + n0 + tc];
    }
    __syncthreads();
    ushort* Wz = wtbf + (size_t)z * F_IN * F_IN;
#pragma unroll
    for (int q = 0; q < 4; ++q) {
      int r = tr + q * 8;
      Wz[(size_t)(n0 + r) * F_IN + k0 + tc] = f2bf(tile[tc][r]);
    }
  } else {
    // ---- x cast/pad ----
    int cb = bid - P1_CONVT_END;
    int z = cb >= 20096;
    int cb2 = cb - z * 20096;
    const float* in = z ? x1 : x0;
    size_t i = ((size_t)cb2 * 256 + t) * 4;
    int row = (int)(i >> 10);
    ushort4 o;
    if (row < N_NODES) {
      float4 v = *(const float4*)(in + i);
      o.x = f2bf(v.x); o.y = f2bf(v.y); o.z = f2bf(v.z); o.w = f2bf(v.w);
    } else {
      o.x = o.y = o.z = o.w = 0;
    }
    *(ushort4*)(xbf + (size_t)z * N_PAD * F_IN + i) = o;
  }
}

// ========== bf16 MFMA GEMM, BK=32 (m97 structure), LDS-cached dinv epilogue ==========
// stores hs[row] = rsqrt(cnt[row]+1) * (x @ W)[row]  (bf16)
__global__ __launch_bounds__(256) void gemm2(const ushort* __restrict__ A,
                                             const ushort* __restrict__ Bt,
                                             const int* __restrict__ cnt,
                                             ushort* __restrict__ C) {
  const int bid = blockIdx.x;
  const int swz = (bid & 7) * (NWG_GEMM / 8) + (bid >> 3);
  const int br  = swz / (ROWB * 8);
  const int rem = swz - br * (ROWB * 8);
  const int rowb = rem >> 3, colb = rem & 7;

  const ushort* Az = A + (size_t)br * N_PAD * F_IN;
  const ushort* Bz = Bt + (size_t)br * F_IN * F_IN;
  ushort* Cz = C + (size_t)br * N_PAD * F_IN;
  const int* cz = cnt + br * N_NODES;

  __shared__ ushort lA[128 * 32];
  __shared__ ushort lB[128 * 32];
  const int t = threadIdx.x;
  const int lane = t & 63;
  const int w = t >> 6;
  const int wr = w >> 1, wc = w & 1;
  const int brow = rowb * 128;
  const int bcol = colb * 128;

  const int si = w * 2;
  const int srow0 = si * 16 + (lane >> 2);
  const int srow1 = (si + 1) * 16 + (lane >> 2);
  const int skk = (lane & 3) * 8;
  const ushort* gA0 = Az + (size_t)(brow + srow0) * F_IN + skk;
  const ushort* gA1 = Az + (size_t)(brow + srow1) * F_IN + skk;
  const ushort* gB0 = Bz + (size_t)(bcol + srow0) * F_IN + skk;
  const ushort* gB1 = Bz + (size_t)(bcol + srow1) * F_IN + skk;
  ushort* lA0 = lA + si * 512;
  ushort* lA1 = lA + (si + 1) * 512;
  ushort* lB0 = lB + si * 512;
  ushort* lB1 = lB + (si + 1) * 512;

  f32x4 acc[4][4] = {};
  const int frow = lane & 15;
  const int fk = (lane >> 4) * 8;

  for (int k0 = 0; k0 < F_IN; k0 += 32) {
    __builtin_amdgcn_global_load_lds((const __attribute__((address_space(1))) void*)(gA0 + k0),
                                     (__attribute__((address_space(3))) void*)lA0, 16, 0, 0);
    __builtin_amdgcn_global_load_lds((const __attribute__((address_space(1))) void*)(gA1 + k0),
                                     (__attribute__((address_space(3))) void*)lA1, 16, 0, 0);
    __builtin_amdgcn_global_load_lds((const __attribute__((address_space(1))) void*)(gB0 + k0),
                                     (__attribute__((address_space(3))) void*)lB0, 16, 0, 0);
    __builtin_amdgcn_global_load_lds((const __attribute__((address_space(1))) void*)(gB1 + k0),
                                     (__attribute__((address_space(3))) void*)lB1, 16, 0, 0);
    __syncthreads();
    bf16x8 af[4], bfr[4];
#pragma unroll
    for (int m = 0; m < 4; ++m)
      af[m] = *(const bf16x8*)(lA + (wr * 64 + m * 16 + frow) * 32 + fk);
#pragma unroll
    for (int n = 0; n < 4; ++n)
      bfr[n] = *(const bf16x8*)(lB + (wc * 64 + n * 16 + frow) * 32 + fk);
#pragma unroll
    for (int m = 0; m < 4; ++m)
#pragma unroll
      for (int n = 0; n < 4; ++n)
        acc[m][n] = __builtin_amdgcn_mfma_f32_16x16x32_bf16(af[m], bfr[n], acc[m][n], 0, 0, 0);
    __syncthreads();
  }

  // cache the block's 128 row-dinv values in LDS (reuse lA; K-loop ended with barrier)
  float* ldv = (float*)lA;
  if (t < 128) {
    int row = brow + t;
    ldv[t] = (row < N_NODES) ? rsqrtf((float)(cz[row] + 1)) : 0.f;
  }
  __syncthreads();

#pragma unroll
  for (int m = 0; m < 4; ++m) {
    const int r0 = wr * 64 + m * 16 + (lane >> 4) * 4;
#pragma unroll
    for (int j = 0; j < 4; ++j) {
      const float dv = ldv[r0 + j];
      const int row = brow + r0 + j;
#pragma unroll
      for (int n = 0; n < 4; ++n) {
        const int col = bcol + wc * 64 + n * 16 + (lane & 15);
        Cz[(size_t)row * F_IN + col] = f2bf(acc[m][n][j] * dv);
      }
    }
  }
}

// ===== GCN aggregate + mean-pool fused, low-atomic, 4-edge-unrolled gather =====
__global__ __launch_bounds__(256) void gcn_agg_pool(const ushort* __restrict__ hs,
                                                    const int* __restrict__ cnt,
                                                    const int* __restrict__ ell,
                                                    const int* __restrict__ bt0,
                                                    const int* __restrict__ bt1,
                                                    const float* __restrict__ b0,
                                                    const float* __restrict__ b1,
                                                    float* __restrict__ pool) {
  __shared__ float lp[F_IN];
  const int g = blockIdx.x;
  const int slice = blockIdx.y;
  const int z = blockIdx.z;
  const int sub = threadIdx.x >> 7;     // 2-node parallel
  const int lt = threadIdx.x & 127;     // 8 features each
  const int* batch = z ? bt1 : bt0;
  const ushort* hz = hs + (size_t)z * N_PAD * F_IN;
  const int* cz = cnt + z * N_NODES;
  const float* bias = z ? b1 : b0;

  int lo = lower_bound_i(batch, N_NODES, g);
  int hi = lower_bound_i(batch, N_NODES, g + 1);
  int per = (hi - lo + S_SLICES - 1) / S_SLICES;
  int a = lo + slice * per;
  int b = min(a + per, hi);
  if (a >= b) return;   // uniform per block

  float bv[8];
  *(float4*)(bv)     = ((const float4*)bias)[lt * 2];
  *(float4*)(bv + 4) = ((const float4*)bias)[lt * 2 + 1];

  float pp[8] = {};
  for (int node = a + sub; node < b; node += 2) {
    const int deg = cz[node];
    const float din = rsqrtf((float)(deg + 1));
    bf16x8 hv = ((const bf16x8*)(hz + (size_t)node * F_IN))[lt];
    float acc[8];
#pragma unroll
    for (int j = 0; j < 8; ++j) acc[j] = bf2f((ushort)hv[j]);
    const int* el = ell + ((size_t)z * N_NODES + node) * ELL_CAP;
    const int ne = min(deg, ELL_CAP);
    int e = 0;
    for (; e + 4 <= ne; e += 4) {
      int4 sx = *(const int4*)(el + e);   // ELL rows are 256B-aligned, e % 4 == 0
      bf16x8 v0 = ((const bf16x8*)(hz + (size_t)sx.x * F_IN))[lt];
      bf16x8 v1 = ((const bf16x8*)(hz + (size_t)sx.y * F_IN))[lt];
      bf16x8 v2 = ((const bf16x8*)(hz + (size_t)sx.z * F_IN))[lt];
      bf16x8 v3 = ((const bf16x8*)(hz + (size_t)sx.w * F_IN))[lt];
#pragma unroll
      for (int j = 0; j < 8; ++j)
        acc[j] += (bf2f((ushort)v0[j]) + bf2f((ushort)v1[j])) +
                  (bf2f((ushort)v2[j]) + bf2f((ushort)v3[j]));
    }
    for (; e < ne; ++e) {
      int s0 = el[e];
      bf16x8 v0 = ((const bf16x8*)(hz + (size_t)s0 * F_IN))[lt];
#pragma unroll
      for (int j = 0; j < 8; ++j) acc[j] += bf2f((ushort)v0[j]);
    }
#pragma unroll
    for (int j = 0; j < 8; ++j) pp[j] += leaky(din * acc[j] + bv[j]);
  }

  // combine the two subs in LDS, then one flush per block
  if (sub == 0) {
    *(float4*)(&lp[lt * 8])     = *(const float4*)(pp);
    *(float4*)(&lp[lt * 8 + 4]) = *(const float4*)(pp + 4);
  }
  __syncthreads();
  if (sub == 1) {
#pragma unroll
    for (int j = 0; j < 8; ++j) lp[lt * 8 + j] += pp[j];
  }
  __syncthreads();
  float* pg = pool + ((size_t)z * N_GRAPHS + g) * F_IN;
#pragma unroll
  for (int q = 0; q < 4; ++q) {
    int i = threadIdx.x + q * 256;
    atomicAdd(&pg[i], lp[i]);
  }
}

// ================= T1: conv_reduce | fc, fused =================
__global__ __launch_bounds__(256) void tail1(const float* __restrict__ pmax,
                                             const float* __restrict__ cb0, const float* __restrict__ cb1,
                                             const float* __restrict__ cb2, const float* __restrict__ cb3,
                                             const float* __restrict__ pool,
                                             const int* __restrict__ bt0, const int* __restrict__ bt1,
                                             const float* __restrict__ W0, const float* __restrict__ W1,
                                             const float* __restrict__ fb0, const float* __restrict__ fb1,
                                             float* __restrict__ combined) {
  __shared__ float p[2][F_IN];
  const int bid = blockIdx.x;
  const int t = threadIdx.x;
  if (bid < 32) {
    int i = bid * 256 + t;
    int br = i >> 11;
    int g = (i >> 7) & 15;
    int d = i & 127;
    const float* pm = pmax + ((size_t)(br * N_GRAPHS + g) * N_CCH) * D_OUT + d;
    float best = -3.4e38f;
#pragma unroll
    for (int ch = 0; ch < N_CCH; ++ch) best = fmaxf(best, pm[ch * D_OUT]);
    const float* bias = br == 0 ? cb0 : br == 1 ? cb1 : br == 2 ? cb2 : cb3;
    combined[g * (6 * D_OUT) + 2 * D_OUT + br * D_OUT + d] = leaky(best + bias[d]);
  } else {
    int idx = (bid - 32) * 2 + (t >> 7);
    int z = idx >> 4, g = idx & 15;
    int tt = t & 127, sub = t >> 7;
    const int* batch = z ? bt1 : bt0;
    const float* W = z ? W1 : W0;
    const float* bias = z ? fb1 : fb0;
    int lo = lower_bound_i(batch, N_NODES, g);
    int hi = lower_bound_i(batch, N_NODES, g + 1);
    float inv = 1.0f / (float)max(hi - lo, 1);
    const float* pg = pool + ((size_t)z * N_GRAPHS + g) * F_IN;
    for (int k = tt; k < F_IN; k += 128) p[sub][k] = pg[k] * inv;
    __syncthreads();
    float acc = 0.f;
    for (int k = 0; k < F_IN; ++k) acc = fmaf(p[sub][k], W[k * D_OUT + tt], acc);
    combined[g * (6 * D_OUT) + z * D_OUT + tt] = leaky(acc + bias[tt]);
  }
}

// ================= final linear =================
__global__ __launch_bounds__(256) void final_kernel(const float* __restrict__ combined,
                                                    const float* __restrict__ Wf,
                                                    const float* __restrict__ bf,
                                                    float* __restrict__ out) {
  const int g = blockIdx.x;
  const int t = threadIdx.x;
  float acc = 0.f;
  for (int k = t; k < 6 * D_OUT; k += 256) acc = fmaf(combined[g * 6 * D_OUT + k], Wf[k], acc);
  __shared__ float red[256];
  red[t] = acc;
  __syncthreads();
  for (int s = 128; s > 0; s >>= 1) {
    if (t < s) red[t] += red[t + s];
    __syncthreads();
  }
  if (t == 0) out[g] = red[0] + bf[0];
}

extern "C" void kernel_launch(void* const* d_in, const int* in_sizes, int n_in,
                              void* d_out, int out_size, void* d_ws, size_t ws_size,
                              hipStream_t stream) {
  const float* p1x  = (const float*)d_in[0];
  const int*   e1   = (const int*)d_in[1];
  const int*   bt1  = (const int*)d_in[2];
  const float* p2x  = (const float*)d_in[3];
  const int*   e2   = (const int*)d_in[4];
  const int*   bt2  = (const int*)d_in[5];
  const float* m1s  = (const float*)d_in[6];
  const float* m1f  = (const float*)d_in[7];
  const float* m2s  = (const float*)d_in[8];
  const float* m2f  = (const float*)d_in[9];
  const float* Wg1  = (const float*)d_in[10];
  const float* bg1  = (const float*)d_in[11];
  const float* Wfc1 = (const float*)d_in[12];
  const float* bfc1 = (const float*)d_in[13];
  const float* Wg2  = (const float*)d_in[14];
  const float* bg2  = (const float*)d_in[15];
  const float* Wfc2 = (const float*)d_in[16];
  const float* bfc2 = (const float*)d_in[17];
  const float* Wm1s = (const float*)d_in[18];
  const float* bm1s = (const float*)d_in[19];
  const float* Wm1f = (const float*)d_in[20];
  const float* bm1f = (const float*)d_in[21];
  const float* Wm2s = (const float*)d_in[22];
  const float* bm2s = (const float*)d_in[23];
  const float* Wm2f = (const float*)d_in[24];
  const float* bm2f = (const float*)d_in[25];
  const float* Wfin = (const float*)d_in[26];
  const float* bfin = (const float*)d_in[27];
  float* out = (float*)d_out;

  char* base = (char*)d_ws;
  size_t off = 0;
  auto alloc = [&](size_t bytes) -> void* {
    void* p = base + off;
    off = (off + bytes + 255) & ~(size_t)255;
    return p;
  };
  ushort* xbf    = (ushort*)alloc((size_t)2 * N_PAD * F_IN * 2);
  ushort* wtbf   = (ushort*)alloc((size_t)2 * F_IN * F_IN * 2);
  ushort* h      = (ushort*)alloc((size_t)2 * N_PAD * F_IN * 2);
  // contiguous zero-init region: cnt, pool
  size_t zoff0 = off;
  int*    cnt    = (int*)alloc((size_t)2 * N_NODES * 4);
  float*  pool   = (float*)alloc((size_t)2 * N_GRAPHS * F_IN * 4);
  size_t zbytes = off - zoff0;
  int*    ell    = (int*)alloc((size_t)2 * N_NODES * ELL_CAP * 4);
  float*  combined = (float*)alloc((size_t)N_GRAPHS * 6 * D_OUT * 4);
  float*  pmax   = (float*)alloc((size_t)4 * N_GRAPHS * N_CCH * D_OUT * 4);
  (void)ws_size; (void)in_sizes; (void)n_in; (void)out_size;

  hipMemsetAsync((char*)base + zoff0, 0, zbytes, stream);

  // P1: conv_mfma | fill_ell | convT | cast  (one fused launch)
  p1_fused<<<P1_CAST_END, 256, P1_SMEM, stream>>>(
      m1s, m1f, m2s, m2f, Wm1s, Wm1f, Wm2s, Wm2f, pmax,
      e1, e2, cnt, ell,
      Wg1, Wg2, wtbf,
      p1x, p2x, xbf);

  gemm2<<<NWG_GEMM, 256, 0, stream>>>(xbf, wtbf, cnt, h);

  gcn_agg_pool<<<dim3(N_GRAPHS, S_SLICES, 2), 256, 0, stream>>>(h, cnt, ell, bt1, bt2, bg1, bg2, pool);

  tail1<<<48, 256, 0, stream>>>(pmax, bm1s, bm1f, bm2s, bm2f,
                                pool, bt1, bt2, Wfc1, Wfc2, bfc1, bfc2, combined);

  final_kernel<<<N_GRAPHS, 256, 0, stream>>>(combined, Wfin, bfin, out);
}

// Round 11
// 356.266 us; speedup vs baseline: 1.3464x; 1.0033x over previous
//
#include <hip/hip_runtime.h>
#include <cstdint>
#include <cstddef>

constexpr int N_NODES  = 20000;
constexpr int N_PAD    = 20096;   // 157 * 128
constexpr int N_EDGES  = 160000;
constexpr int N_GRAPHS = 16;
constexpr int SEQ_L    = 2048;
constexpr int F_IN     = 1024;
constexpr int D_OUT    = 128;
constexpr int N_DESC   = 80;
constexpr int K_PAD    = 104;     // conv: 80 padded to 96 for MFMA, 104 stride for banks
constexpr int N_CCH    = 16;      // conv: L-chunks of 128
constexpr int ELL_CAP  = 64;      // max degree capacity (Poisson(8): P(>64) ~ 1e-10)
constexpr int S_SLICES = 32;      // agg: node slices per graph
constexpr int ROWB     = N_PAD / 128;      // 157
constexpr int NWG_GEMM = 2 * ROWB * 8;     // 2512, divisible by 8
constexpr float SLOPE  = 0.01f;

// P1 fused-kernel block ranges
constexpr int P1_CONV_END  = 1024;                    // 16 ch * 16 g * 4 br
constexpr int P1_FILL_END  = P1_CONV_END + 2 * 625;   // 160000/256 = 625 per branch
constexpr int P1_CONVT_END = P1_FILL_END + 2 * 1024;  // 32*32 per branch
constexpr int P1_CAST_END  = P1_CONVT_END + 2 * 20096;
constexpr int P1_SMEM      = 53248;                   // 2 * 128*104*2 bytes

typedef short bf16x8 __attribute__((ext_vector_type(8)));
typedef float f32x4  __attribute__((ext_vector_type(4)));

__device__ __forceinline__ float leaky(float x) { return x > 0.f ? x : SLOPE * x; }
__device__ __forceinline__ ushort f2bf(float f) {
  uint32_t u = __float_as_uint(f);
  uint32_t r = (u + 0x7FFFu + ((u >> 16) & 1u)) >> 16;
  return (ushort)r;
}
__device__ __forceinline__ float bf2f(ushort u) { return __uint_as_float(((uint32_t)u) << 16); }

__device__ __forceinline__ int lower_bound_i(const int* __restrict__ arr, int n, int val) {
  int lo = 0, hi = n;
  while (lo < hi) { int mid = (lo + hi) >> 1; if (arr[mid] < val) lo = mid + 1; else hi = mid; }
  return lo;
}

// ================= P1: conv_mfma | fill_ell | convT | cast_pad (one launch) =================
__global__ __launch_bounds__(256) void p1_fused(
    const float* __restrict__ m0, const float* __restrict__ m1,
    const float* __restrict__ m2, const float* __restrict__ m3,
    const float* __restrict__ Wc0, const float* __restrict__ Wc1,
    const float* __restrict__ Wc2, const float* __restrict__ Wc3,
    float* __restrict__ pmax,
    const int* __restrict__ e0, const int* __restrict__ e1,
    int* __restrict__ cnt, int* __restrict__ ell,
    const float* __restrict__ Wg0, const float* __restrict__ Wg1,
    ushort* __restrict__ wtbf,
    const float* __restrict__ x0, const float* __restrict__ x1,
    ushort* __restrict__ xbf) {
  extern __shared__ char smem[];
  const int bid = blockIdx.x;
  const int t = threadIdx.x;

  if (bid < P1_CONV_END) {
    // ---- conv1d(k=1) via MFMA: [128 L-rows x 80] @ [80 x 128], max over rows ----
    ushort* lA = (ushort*)smem;                 // [128][K_PAD]
    ushort* lB = (ushort*)(smem + 26624);       // [128 col][K_PAD]
    float*  smax = (float*)smem;                // aliases lA after compute
    const int ch = bid & 15, g = (bid >> 4) & 15, br = bid >> 8;
    const float* m = br == 0 ? m0 : br == 1 ? m1 : br == 2 ? m2 : m3;
    const float* W = br == 0 ? Wc0 : br == 1 ? Wc1 : br == 2 ? Wc2 : Wc3;
    const int lane = t & 63, w = t >> 6;

    for (int i = t; i < N_DESC * D_OUT; i += 256) {
      int k = i >> 7, col = i & 127;
      lB[col * K_PAD + k] = f2bf(W[i]);
    }
    for (int i = t; i < 128 * 16; i += 256) {
      int col = i >> 4, k = 80 + (i & 15);
      lB[col * K_PAD + k] = 0;
    }
    const float4* mg4 = (const float4*)(m + ((size_t)g * SEQ_L + (size_t)ch * 128) * N_DESC);
#pragma unroll
    for (int j = 0; j < 10; ++j) {
      int fi = t + j * 256;
      int row = fi / 20, off = fi - row * 20;
      float4 v = mg4[fi];
      ushort4 o;
      o.x = f2bf(v.x); o.y = f2bf(v.y); o.z = f2bf(v.z); o.w = f2bf(v.w);
      *(ushort4*)(lA + row * K_PAD + off * 4) = o;
    }
    if (t < 128) {
      ushort4 z4 = {0, 0, 0, 0};
      *(ushort4*)(lA + t * K_PAD + 80) = z4;
      *(ushort4*)(lA + t * K_PAD + 84) = z4;
      *(ushort4*)(lA + t * K_PAD + 88) = z4;
      *(ushort4*)(lA + t * K_PAD + 92) = z4;
    }
    __syncthreads();

    const int frow = lane & 15, fk = (lane >> 4) * 8;
    f32x4 acc[2][8] = {};
#pragma unroll
    for (int ks = 0; ks < 3; ++ks) {
      bf16x8 af[2], bfr[8];
#pragma unroll
      for (int mm = 0; mm < 2; ++mm)
        af[mm] = *(const bf16x8*)(lA + (w * 32 + mm * 16 + frow) * K_PAD + ks * 32 + fk);
#pragma unroll
      for (int n = 0; n < 8; ++n)
        bfr[n] = *(const bf16x8*)(lB + (n * 16 + frow) * K_PAD + ks * 32 + fk);
#pragma unroll
      for (int mm = 0; mm < 2; ++mm)
#pragma unroll
        for (int n = 0; n < 8; ++n)
          acc[mm][n] = __builtin_amdgcn_mfma_f32_16x16x32_bf16(af[mm], bfr[n], acc[mm][n], 0, 0, 0);
    }
    __syncthreads();

#pragma unroll
    for (int n = 0; n < 8; ++n) {
      float v = acc[0][n][0];
#pragma unroll
      for (int j = 1; j < 4; ++j) v = fmaxf(v, acc[0][n][j]);
#pragma unroll
      for (int j = 0; j < 4; ++j) v = fmaxf(v, acc[1][n][j]);
      v = fmaxf(v, __shfl_xor(v, 16, 64));
      v = fmaxf(v, __shfl_xor(v, 32, 64));
      if (lane < 16) smax[w * D_OUT + n * 16 + lane] = v;
    }
    __syncthreads();
    if (t < D_OUT) {
      float v = fmaxf(fmaxf(smax[t], smax[D_OUT + t]),
                      fmaxf(smax[2 * D_OUT + t], smax[3 * D_OUT + t]));
      pmax[(((size_t)br * N_GRAPHS + g) * N_CCH + ch) * D_OUT + t] = v;
    }
  } else if (bid < P1_FILL_END) {
    // ---- build ELL adjacency ----
    int fb = bid - P1_CONV_END;
    int z = fb >= 625;
    int i = (fb - z * 625) * 256 + t;
    const int* src = z ? e1 : e0;
    const int* dst = src + N_EDGES;
    int d = dst[i];
    int pos = atomicAdd(&cnt[z * N_NODES + d], 1);
    if (pos < ELL_CAP) ell[((size_t)z * N_NODES + d) * ELL_CAP + pos] = src[i];
  } else if (bid < P1_CONVT_END) {
    // ---- W [K=1024][N=1024] f32 -> Wt [N][K] bf16 ----
    float (*tile)[33] = (float(*)[33])smem;
    int cb = bid - P1_FILL_END;
    int z = cb >= 1024;
    int cb2 = cb - z * 1024;
    const float* W = z ? Wg1 : Wg0;
    const int k0 = (cb2 & 31) * 32, n0 = (cb2 >> 5) * 32;
    const int tc = t & 31, tr = t >> 5;
#pragma unroll
    for (int q = 0; q < 4; ++q) {
      int r = tr + q * 8;
      tile[r][tc] = W[(size_t)(k0 + r) * F_IN + n0 + tc];
    }
    __syncthreads();
    ushort* Wz = wtbf + (size_t)z * F_IN * F_IN;
#pragma unroll
    for (int q = 0; q < 4; ++q) {
      int r = tr + q * 8;
      Wz[(size_t)(n0 + r) * F_IN + k0 + tc] = f2bf(tile[tc][r]);
    }
  } else {
    // ---- x cast/pad ----
    int cb = bid - P1_CONVT_END;
    int z = cb >= 20096;
    int cb2 = cb - z * 20096;
    const float* in = z ? x1 : x0;
    size_t i = ((size_t)cb2 * 256 + t) * 4;
    int row = (int)(i >> 10);
    ushort4 o;
    if (row < N_NODES) {
      float4 v = *(const float4*)(in + i);
      o.x = f2bf(v.x); o.y = f2bf(v.y); o.z = f2bf(v.z); o.w = f2bf(v.w);
    } else {
      o.x = o.y = o.z = o.w = 0;
    }
    *(ushort4*)(xbf + (size_t)z * N_PAD * F_IN + i) = o;
  }
}

// ========== bf16 MFMA GEMM, BK=32 (m97 structure), LDS-cached dinv epilogue ==========
// stores hs[row] = rsqrt(cnt[row]+1) * (x @ W)[row]  (bf16)
__global__ __launch_bounds__(256) void gemm2(const ushort* __restrict__ A,
                                             const ushort* __restrict__ Bt,
                                             const int* __restrict__ cnt,
                                             ushort* __restrict__ C) {
  const int bid = blockIdx.x;
  const int swz = (bid & 7) * (NWG_GEMM / 8) + (bid >> 3);
  const int br  = swz / (ROWB * 8);
  const int rem = swz - br * (ROWB * 8);
  const int rowb = rem >> 3, colb = rem & 7;

  const ushort* Az = A + (size_t)br * N_PAD * F_IN;
  const ushort* Bz = Bt + (size_t)br * F_IN * F_IN;
  ushort* Cz = C + (size_t)br * N_PAD * F_IN;
  const int* cz = cnt + br * N_NODES;

  __shared__ ushort lA[128 * 32];
  __shared__ ushort lB[128 * 32];
  const int t = threadIdx.x;
  const int lane = t & 63;
  const int w = t >> 6;
  const int wr = w >> 1, wc = w & 1;
  const int brow = rowb * 128;
  const int bcol = colb * 128;

  const int si = w * 2;
  const int srow0 = si * 16 + (lane >> 2);
  const int srow1 = (si + 1) * 16 + (lane >> 2);
  const int skk = (lane & 3) * 8;
  const ushort* gA0 = Az + (size_t)(brow + srow0) * F_IN + skk;
  const ushort* gA1 = Az + (size_t)(brow + srow1) * F_IN + skk;
  const ushort* gB0 = Bz + (size_t)(bcol + srow0) * F_IN + skk;
  const ushort* gB1 = Bz + (size_t)(bcol + srow1) * F_IN + skk;
  ushort* lA0 = lA + si * 512;
  ushort* lA1 = lA + (si + 1) * 512;
  ushort* lB0 = lB + si * 512;
  ushort* lB1 = lB + (si + 1) * 512;

  f32x4 acc[4][4] = {};
  const int frow = lane & 15;
  const int fk = (lane >> 4) * 8;

  for (int k0 = 0; k0 < F_IN; k0 += 32) {
    __builtin_amdgcn_global_load_lds((const __attribute__((address_space(1))) void*)(gA0 + k0),
                                     (__attribute__((address_space(3))) void*)lA0, 16, 0, 0);
    __builtin_amdgcn_global_load_lds((const __attribute__((address_space(1))) void*)(gA1 + k0),
                                     (__attribute__((address_space(3))) void*)lA1, 16, 0, 0);
    __builtin_amdgcn_global_load_lds((const __attribute__((address_space(1))) void*)(gB0 + k0),
                                     (__attribute__((address_space(3))) void*)lB0, 16, 0, 0);
    __builtin_amdgcn_global_load_lds((const __attribute__((address_space(1))) void*)(gB1 + k0),
                                     (__attribute__((address_space(3))) void*)lB1, 16, 0, 0);
    __syncthreads();
    bf16x8 af[4], bfr[4];
#pragma unroll
    for (int m = 0; m < 4; ++m)
      af[m] = *(const bf16x8*)(lA + (wr * 64 + m * 16 + frow) * 32 + fk);
#pragma unroll
    for (int n = 0; n < 4; ++n)
      bfr[n] = *(const bf16x8*)(lB + (wc * 64 + n * 16 + frow) * 32 + fk);
#pragma unroll
    for (int m = 0; m < 4; ++m)
#pragma unroll
      for (int n = 0; n < 4; ++n)
        acc[m][n] = __builtin_amdgcn_mfma_f32_16x16x32_bf16(af[m], bfr[n], acc[m][n], 0, 0, 0);
    __syncthreads();
  }

  // cache the block's 128 row-dinv values in LDS (reuse lA; K-loop ended with barrier)
  float* ldv = (float*)lA;
  if (t < 128) {
    int row = brow + t;
    ldv[t] = (row < N_NODES) ? rsqrtf((float)(cz[row] + 1)) : 0.f;
  }
  __syncthreads();

#pragma unroll
  for (int m = 0; m < 4; ++m) {
    const int r0 = wr * 64 + m * 16 + (lane >> 4) * 4;
#pragma unroll
    for (int j = 0; j < 4; ++j) {
      const float dv = ldv[r0 + j];
      const int row = brow + r0 + j;
#pragma unroll
      for (int n = 0; n < 4; ++n) {
        const int col = bcol + wc * 64 + n * 16 + (lane & 15);
        Cz[(size_t)row * F_IN + col] = f2bf(acc[m][n][j] * dv);
      }
    }
  }
}

// ===== GCN aggregate + mean-pool fused, feature-split for max TLP =====
// block = (graph g, slice, fhalf, branch z); 4 subs x 64 lanes x 8 features = 4 nodes
// in flight over 512 features; per-block atomic flush = 512 floats ->
// total atomics unchanged (~1M) while grid doubles to 2048 blocks (32 waves/CU).
__global__ __launch_bounds__(256) void gcn_agg_pool(const ushort* __restrict__ hs,
                                                    const int* __restrict__ cnt,
                                                    const int* __restrict__ ell,
                                                    const int* __restrict__ bt0,
                                                    const int* __restrict__ bt1,
                                                    const float* __restrict__ b0,
                                                    const float* __restrict__ b1,
                                                    float* __restrict__ pool) {
  __shared__ float lp[4][512];
  const int g = blockIdx.x;
  const int slice = blockIdx.y >> 1;
  const int fhalf = blockIdx.y & 1;
  const int z = blockIdx.z;
  const int sub = threadIdx.x >> 6;     // 0..3: node parity
  const int lane = threadIdx.x & 63;
  const int fc = fhalf * 64 + lane;     // bf16x8 chunk index within a row (0..127)
  const int* batch = z ? bt1 : bt0;
  const ushort* hz = hs + (size_t)z * N_PAD * F_IN;
  const int* cz = cnt + z * N_NODES;
  const float* bias = z ? b1 : b0;

  int lo = lower_bound_i(batch, N_NODES, g);
  int hi = lower_bound_i(batch, N_NODES, g + 1);
  int per = (hi - lo + S_SLICES - 1) / S_SLICES;
  int a = lo + slice * per;
  int b = min(a + per, hi);
  if (a >= b) return;   // uniform per block

  float bv[8];
  *(float4*)(bv)     = ((const float4*)bias)[fc * 2];
  *(float4*)(bv + 4) = ((const float4*)bias)[fc * 2 + 1];

  float pp[8] = {};
  for (int node = a + sub; node < b; node += 4) {
    const int deg = cz[node];
    const float din = rsqrtf((float)(deg + 1));
    bf16x8 hv = ((const bf16x8*)(hz + (size_t)node * F_IN))[fc];
    float acc[8];
#pragma unroll
    for (int j = 0; j < 8; ++j) acc[j] = bf2f((ushort)hv[j]);
    const int* el = ell + ((size_t)z * N_NODES + node) * ELL_CAP;
    const int ne = min(deg, ELL_CAP);
    int e = 0;
    for (; e + 4 <= ne; e += 4) {
      int4 sx = *(const int4*)(el + e);   // ELL rows are 256B-aligned, e % 4 == 0
      bf16x8 v0 = ((const bf16x8*)(hz + (size_t)sx.x * F_IN))[fc];
      bf16x8 v1 = ((const bf16x8*)(hz + (size_t)sx.y * F_IN))[fc];
      bf16x8 v2 = ((const bf16x8*)(hz + (size_t)sx.z * F_IN))[fc];
      bf16x8 v3 = ((const bf16x8*)(hz + (size_t)sx.w * F_IN))[fc];
#pragma unroll
      for (int j = 0; j < 8; ++j)
        acc[j] += (bf2f((ushort)v0[j]) + bf2f((ushort)v1[j])) +
                  (bf2f((ushort)v2[j]) + bf2f((ushort)v3[j]));
    }
    for (; e < ne; ++e) {
      int s0 = el[e];
      bf16x8 v0 = ((const bf16x8*)(hz + (size_t)s0 * F_IN))[fc];
#pragma unroll
      for (int j = 0; j < 8; ++j) acc[j] += bf2f((ushort)v0[j]);
    }
#pragma unroll
    for (int j = 0; j < 8; ++j) pp[j] += leaky(din * acc[j] + bv[j]);
  }

  // per-sub partials -> LDS, tree-free reduce (each thread sums 2 features), one flush
  *(float4*)(&lp[sub][lane * 8])     = *(const float4*)(pp);
  *(float4*)(&lp[sub][lane * 8 + 4]) = *(const float4*)(pp + 4);
  __syncthreads();
  float* pg = pool + ((size_t)z * N_GRAPHS + g) * F_IN + fhalf * 512;
#pragma unroll
  for (int q = 0; q < 2; ++q) {
    int i = threadIdx.x + q * 256;
    float s = (lp[0][i] + lp[1][i]) + (lp[2][i] + lp[3][i]);
    atomicAdd(&pg[i], s);
  }
}

// ================= T1: conv_reduce | fc, fused =================
__global__ __launch_bounds__(256) void tail1(const float* __restrict__ pmax,
                                             const float* __restrict__ cb0, const float* __restrict__ cb1,
                                             const float* __restrict__ cb2, const float* __restrict__ cb3,
                                             const float* __restrict__ pool,
                                             const int* __restrict__ bt0, const int* __restrict__ bt1,
                                             const float* __restrict__ W0, const float* __restrict__ W1,
                                             const float* __restrict__ fb0, const float* __restrict__ fb1,
                                             float* __restrict__ combined) {
  __shared__ float p[2][F_IN];
  const int bid = blockIdx.x;
  const int t = threadIdx.x;
  if (bid < 32) {
    int i = bid * 256 + t;
    int br = i >> 11;
    int g = (i >> 7) & 15;
    int d = i & 127;
    const float* pm = pmax + ((size_t)(br * N_GRAPHS + g) * N_CCH) * D_OUT + d;
    float best = -3.4e38f;
#pragma unroll
    for (int ch = 0; ch < N_CCH; ++ch) best = fmaxf(best, pm[ch * D_OUT]);
    const float* bias = br == 0 ? cb0 : br == 1 ? cb1 : br == 2 ? cb2 : cb3;
    combined[g * (6 * D_OUT) + 2 * D_OUT + br * D_OUT + d] = leaky(best + bias[d]);
  } else {
    int idx = (bid - 32) * 2 + (t >> 7);
    int z = idx >> 4, g = idx & 15;
    int tt = t & 127, sub = t >> 7;
    const int* batch = z ? bt1 : bt0;
    const float* W = z ? W1 : W0;
    const float* bias = z ? fb1 : fb0;
    int lo = lower_bound_i(batch, N_NODES, g);
    int hi = lower_bound_i(batch, N_NODES, g + 1);
    float inv = 1.0f / (float)max(hi - lo, 1);
    const float* pg = pool + ((size_t)z * N_GRAPHS + g) * F_IN;
    for (int k = tt; k < F_IN; k += 128) p[sub][k] = pg[k] * inv;
    __syncthreads();
    float acc = 0.f;
    for (int k = 0; k < F_IN; ++k) acc = fmaf(p[sub][k], W[k * D_OUT + tt], acc);
    combined[g * (6 * D_OUT) + z * D_OUT + tt] = leaky(acc + bias[tt]);
  }
}

// ================= final linear =================
__global__ __launch_bounds__(256) void final_kernel(const float* __restrict__ combined,
                                                    const float* __restrict__ Wf,
                                                    const float* __restrict__ bf,
                                                    float* __restrict__ out) {
  const int g = blockIdx.x;
  const int t = threadIdx.x;
  float acc = 0.f;
  for (int k = t; k < 6 * D_OUT; k += 256) acc = fmaf(combined[g * 6 * D_OUT + k], Wf[k], acc);
  __shared__ float red[256];
  red[t] = acc;
  __syncthreads();
  for (int s = 128; s > 0; s >>= 1) {
    if (t < s) red[t] += red[t + s];
    __syncthreads();
  }
  if (t == 0) out[g] = red[0] + bf[0];
}

extern "C" void kernel_launch(void* const* d_in, const int* in_sizes, int n_in,
                              void* d_out, int out_size, void* d_ws, size_t ws_size,
                              hipStream_t stream) {
  const float* p1x  = (const float*)d_in[0];
  const int*   e1   = (const int*)d_in[1];
  const int*   bt1  = (const int*)d_in[2];
  const float* p2x  = (const float*)d_in[3];
  const int*   e2   = (const int*)d_in[4];
  const int*   bt2  = (const int*)d_in[5];
  const float* m1s  = (const float*)d_in[6];
  const float* m1f  = (const float*)d_in[7];
  const float* m2s  = (const float*)d_in[8];
  const float* m2f  = (const float*)d_in[9];
  const float* Wg1  = (const float*)d_in[10];
  const float* bg1  = (const float*)d_in[11];
  const float* Wfc1 = (const float*)d_in[12];
  const float* bfc1 = (const float*)d_in[13];
  const float* Wg2  = (const float*)d_in[14];
  const float* bg2  = (const float*)d_in[15];
  const float* Wfc2 = (const float*)d_in[16];
  const float* bfc2 = (const float*)d_in[17];
  const float* Wm1s = (const float*)d_in[18];
  const float* bm1s = (const float*)d_in[19];
  const float* Wm1f = (const float*)d_in[20];
  const float* bm1f = (const float*)d_in[21];
  const float* Wm2s = (const float*)d_in[22];
  const float* bm2s = (const float*)d_in[23];
  const float* Wm2f = (const float*)d_in[24];
  const float* bm2f = (const float*)d_in[25];
  const float* Wfin = (const float*)d_in[26];
  const float* bfin = (const float*)d_in[27];
  float* out = (float*)d_out;

  char* base = (char*)d_ws;
  size_t off = 0;
  auto alloc = [&](size_t bytes) -> void* {
    void* p = base + off;
    off = (off + bytes + 255) & ~(size_t)255;
    return p;
  };
  ushort* xbf    = (ushort*)alloc((size_t)2 * N_PAD * F_IN * 2);
  ushort* wtbf   = (ushort*)alloc((size_t)2 * F_IN * F_IN * 2);
  ushort* h      = (ushort*)alloc((size_t)2 * N_PAD * F_IN * 2);
  // contiguous zero-init region: cnt, pool
  size_t zoff0 = off;
  int*    cnt    = (int*)alloc((size_t)2 * N_NODES * 4);
  float*  pool   = (float*)alloc((size_t)2 * N_GRAPHS * F_IN * 4);
  size_t zbytes = off - zoff0;
  int*    ell    = (int*)alloc((size_t)2 * N_NODES * ELL_CAP * 4);
  float*  combined = (float*)alloc((size_t)N_GRAPHS * 6 * D_OUT * 4);
  float*  pmax   = (float*)alloc((size_t)4 * N_GRAPHS * N_CCH * D_OUT * 4);
  (void)ws_size; (void)in_sizes; (void)n_in; (void)out_size;

  hipMemsetAsync((char*)base + zoff0, 0, zbytes, stream);

  // P1: conv_mfma | fill_ell | convT | cast  (one fused launch)
  p1_fused<<<P1_CAST_END, 256, P1_SMEM, stream>>>(
      m1s, m1f, m2s, m2f, Wm1s, Wm1f, Wm2s, Wm2f, pmax,
      e1, e2, cnt, ell,
      Wg1, Wg2, wtbf,
      p1x, p2x, xbf);

  gemm2<<<NWG_GEMM, 256, 0, stream>>>(xbf, wtbf, cnt, h);

  gcn_agg_pool<<<dim3(N_GRAPHS, S_SLICES * 2, 2), 256, 0, stream>>>(h, cnt, ell, bt1, bt2, bg1, bg2, pool);

  tail1<<<48, 256, 0, stream>>>(pmax, bm1s, bm1f, bm2s, bm2f,
                                pool, bt1, bt2, Wfc1, Wfc2, bfc1, bfc2, combined);

  final_kernel<<<N_GRAPHS, 256, 0, stream>>>(combined, Wfin, bfin, out);
}